// Round 1
// baseline (382.297 us; speedup 1.0000x reference)
//
#include <hip/hip_runtime.h>
#include <cstdint>
#include <cstddef>

#define G_    4
#define S_    2048
#define D_    2048
#define E_    64
#define NTOK  (G_ * S_)          // 8192
#define CAPM1 63                 // expert_capacity - 1 (c=0 dropped by [..., 1:])
#define COMBINE_SZ ((size_t)NTOK * E_ * CAPM1)   // 33,030,144
#define KSLICES 4
#define KCHUNK  (D_ / KSLICES)   // 512

// ---------------------------------------------------------------------------
// Stage 1: partial GEMM logits[slice][tok][e] = sum_{k in slice} x[tok][k]*W[k][e]
// Block: 256 threads -> 64 tokens x 64 experts tile, 4x4 per thread.
// Grid: (8192/64, KSLICES) = (128, 4) = 512 blocks.
// ---------------------------------------------------------------------------
__global__ __launch_bounds__(256) void gemm_partial_k(
    const float* __restrict__ x, const float* __restrict__ W,
    float* __restrict__ partial)
{
    __shared__ float xs[16][64];   // [k][token]
    __shared__ float wls[16][64];  // [k][expert]

    const int tid     = threadIdx.x;
    const int tokBase = blockIdx.x * 64;
    const int kBase   = blockIdx.y * KCHUNK;

    const int tt = (tid >> 4) << 2;   // token sub-offset 0..60
    const int ee = (tid & 15) << 2;   // expert sub-offset 0..60

    const int xrow = tid >> 2;        // 0..63
    const int xkq  = (tid & 3) << 2;  // 0,4,8,12
    const int wkr  = tid >> 4;        // 0..15
    const int wec  = (tid & 15) << 2; // 0..60

    float acc[4][4];
#pragma unroll
    for (int i = 0; i < 4; ++i)
#pragma unroll
        for (int j = 0; j < 4; ++j) acc[i][j] = 0.f;

    for (int kc = 0; kc < KCHUNK; kc += 16) {
        const float4 xv = *reinterpret_cast<const float4*>(
            &x[(size_t)(tokBase + xrow) * D_ + (size_t)(kBase + kc + xkq)]);
        const float4 wv = *reinterpret_cast<const float4*>(
            &W[(size_t)(kBase + kc + wkr) * E_ + wec]);
        __syncthreads();   // protect LDS from previous iteration's readers
        xs[xkq + 0][xrow] = xv.x;
        xs[xkq + 1][xrow] = xv.y;
        xs[xkq + 2][xrow] = xv.z;
        xs[xkq + 3][xrow] = xv.w;
        *reinterpret_cast<float4*>(&wls[wkr][wec]) = wv;
        __syncthreads();
#pragma unroll
        for (int k = 0; k < 16; ++k) {
            const float4 xa = *reinterpret_cast<const float4*>(&xs[k][tt]);
            const float4 wb = *reinterpret_cast<const float4*>(&wls[k][ee]);
            acc[0][0] += xa.x * wb.x; acc[0][1] += xa.x * wb.y;
            acc[0][2] += xa.x * wb.z; acc[0][3] += xa.x * wb.w;
            acc[1][0] += xa.y * wb.x; acc[1][1] += xa.y * wb.y;
            acc[1][2] += xa.y * wb.z; acc[1][3] += xa.y * wb.w;
            acc[2][0] += xa.z * wb.x; acc[2][1] += xa.z * wb.y;
            acc[2][2] += xa.z * wb.z; acc[2][3] += xa.z * wb.w;
            acc[3][0] += xa.w * wb.x; acc[3][1] += xa.w * wb.y;
            acc[3][2] += xa.w * wb.z; acc[3][3] += xa.w * wb.w;
        }
    }

    float* dst = partial + (size_t)blockIdx.y * ((size_t)NTOK * E_);
#pragma unroll
    for (int i = 0; i < 4; ++i) {
        float4 v = make_float4(acc[i][0], acc[i][1], acc[i][2], acc[i][3]);
        *reinterpret_cast<float4*>(&dst[(size_t)(tokBase + tt + i) * E_ + ee]) = v;
    }
}

// ---------------------------------------------------------------------------
// Stage 2: reduce K-slices, softmax over E=64 (one wave per token, lane=expert),
// top-2 with lowest-index tie-break (matches jax.lax.top_k).
// ---------------------------------------------------------------------------
__global__ __launch_bounds__(256) void softmax_top2_k(
    const float* __restrict__ partial, const float* __restrict__ b,
    int* __restrict__ e1, int* __restrict__ e2,
    float* __restrict__ g1, float* __restrict__ g2)
{
    const int lane = threadIdx.x & 63;
    const int w    = threadIdx.x >> 6;
    const int tok  = blockIdx.x * 4 + w;

    float v = b[lane];
#pragma unroll
    for (int sl = 0; sl < KSLICES; ++sl)
        v += partial[(size_t)sl * NTOK * E_ + (size_t)tok * E_ + lane];

    float m = v;
#pragma unroll
    for (int off = 32; off >= 1; off >>= 1) m = fmaxf(m, __shfl_xor(m, off));
    float p = expf(v - m);
    float s = p;
#pragma unroll
    for (int off = 32; off >= 1; off >>= 1) s += __shfl_xor(s, off);
    p = p / s;

    // top-1
    float bp = p; int bi = lane;
#pragma unroll
    for (int off = 32; off >= 1; off >>= 1) {
        float po = __shfl_xor(bp, off);
        int   io = __shfl_xor(bi, off);
        if (po > bp || (po == bp && io < bi)) { bp = po; bi = io; }
    }
    // top-2 (exclude bi)
    float p2 = (lane == bi) ? -1.0f : p;
    float bp2 = p2; int bi2 = lane;
#pragma unroll
    for (int off = 32; off >= 1; off >>= 1) {
        float po = __shfl_xor(bp2, off);
        int   io = __shfl_xor(bi2, off);
        if (po > bp2 || (po == bp2 && io < bi2)) { bp2 = po; bi2 = io; }
    }

    if (lane == 0) {
        e1[tok] = bi;  e2[tok] = bi2;
        g1[tok] = bp;  g2[tok] = bp2;
    }
}

// ---------------------------------------------------------------------------
// Stage 3: per-group cumulative position (ballot + LDS wave-prefix) and scatter.
// One block per group g; 1024 threads = 16 waves; each wave owns 64-token
// stretches at wseg*64 (wseg = seg*16 + wid), preserving token order.
// ---------------------------------------------------------------------------
__global__ __launch_bounds__(1024) void route_scatter_k(
    const int* __restrict__ e1, const int* __restrict__ e2,
    const float* __restrict__ g1, const float* __restrict__ g2,
    float* __restrict__ out)
{
    __shared__ int cnt[2][32][64];   // [k][wave-seg][expert]

    const int g    = blockIdx.x;
    const int lane = threadIdx.x & 63;
    const int wid  = threadIdx.x >> 6;   // 0..15
    const unsigned long long ltmask = ((unsigned long long)1 << lane) - 1;

    int myE[2][2];
    int rank[2][2];

#pragma unroll
    for (int seg = 0; seg < 2; ++seg) {
        const int wseg = seg * 16 + wid;
        const int tok  = g * S_ + wseg * 64 + lane;
        const int ea = e1[tok];
        const int eb = e2[tok];
        myE[seg][0] = ea;
        myE[seg][1] = eb;
#pragma unroll
        for (int k = 0; k < 2; ++k) {
            const int me = k ? eb : ea;
            int r = 0;
            for (int e = 0; e < 64; ++e) {
                unsigned long long mask = __ballot(me == e);
                if (lane == e) cnt[k][wseg][e] = __popcll(mask);
                if (me == e)   r = __popcll(mask & ltmask);
            }
            rank[seg][k] = r;
        }
    }
    __syncthreads();

    // exclusive prefix over the 32 wave-segments, per (k, e)
    if (threadIdx.x < 128) {
        const int k = threadIdx.x >> 6;
        const int e = threadIdx.x & 63;
        int run = 0;
        for (int w = 0; w < 32; ++w) {
            int c = cnt[k][w][e];
            cnt[k][w][e] = run;
            run += c;
        }
    }
    __syncthreads();

#pragma unroll
    for (int seg = 0; seg < 2; ++seg) {
        const int wseg = seg * 16 + wid;
        const int tok  = g * S_ + wseg * 64 + lane;
#pragma unroll
        for (int k = 0; k < 2; ++k) {
            const int e   = myE[seg][k];
            const int pos = cnt[k][wseg][e] + rank[seg][k] + 1;  // 1-based
            if (pos <= CAPM1) {                                  // pos in [1,63]
                const float gate = k ? g2[tok] : g1[tok];
                const size_t idx = ((size_t)tok * E_ + e) * CAPM1 + (pos - 1);
                out[idx] = gate;                  // combine_tensor
                out[idx + COMBINE_SZ] = 1.0f;     // dispatch_mask
            }
        }
    }
}

// ---------------------------------------------------------------------------
extern "C" void kernel_launch(void* const* d_in, const int* in_sizes, int n_in,
                              void* d_out, int out_size, void* d_ws, size_t ws_size,
                              hipStream_t stream)
{
    const float* x = (const float*)d_in[0];
    const float* W = (const float*)d_in[1];
    const float* b = (const float*)d_in[2];
    float* out = (float*)d_out;

    // Partial logits (KSLICES * 8192 * 64 f32 = 8 MB) live at the head of
    // d_out BEFORE the memset (stream-ordered: gemm -> softmax -> memset -> scatter).
    float* partial = (float*)d_out;

    // Small per-token arrays in d_ws (128 KB).
    int*   e1 = (int*)d_ws;
    int*   e2 = e1 + NTOK;
    float* g1 = (float*)(e2 + NTOK);
    float* g2 = g1 + NTOK;

    gemm_partial_k<<<dim3(NTOK / 64, KSLICES), 256, 0, stream>>>(x, W, partial);
    softmax_top2_k<<<NTOK / 4, 256, 0, stream>>>(partial, b, e1, e2, g1, g2);
    hipMemsetAsync(d_out, 0, (size_t)out_size * sizeof(float), stream);
    route_scatter_k<<<G_, 1024, 0, stream>>>(e1, e2, g1, g2, out);
}